// Round 7
// baseline (416.184 us; speedup 1.0000x reference)
//
#include <hip/hip_runtime.h>

// SRLoss: loss = mean((inp - avgpool10x10(output))^2) + BCE(output, target)
// output/target: [32,1,1280,1280] f32; inp: [32,1,128,128] f32; out: scalar f32.
//
// R9 post-mortem: asm-volatile preload STILL shows VGPR=44 (impossible if 20
// float4 dests were live) -> hipcc defeated per-wave MLP forcing for the 3rd
// time. Abandoned that arc. Little's law: 12 GB/s/CU == ~10 waves x ~1KB in
// flight at ~850ns. Remaining lever is WAVES (TLP): occupancy has been stuck
// at 30% (~2 blocks/CU) with 4096 churning blocks.
// R10: persistent blocks. Grid = 1024 = exactly 4 blocks/CU (20 waves/CU,
// 62% occ by construction), each block loops over 4 bands with #pragma
// unroll 1 (runtime loop -> R4's proven 44-VGPR body per iteration, no R5
// mega-unroll spill). Signature: OccupancyPercent ~55-62. If occ rises but
// dur stays ~137us -> hard ~3TB/s limiter, XCD-swizzle-or-stop next.
// R11: identical resubmit — R10 bench died to container infra, no data.

#define BATCH 32
#define HH 1280
#define WW 1280
#define PH 128
#define PW 128
#define SC 10
#define NT 320                      // threads per block (5 waves)
#define KD 10                       // float4-pair iterations per thread
#define PD 5                        // software-pipeline depth
#define NB (BATCH * PH)             // 4096 bands
#define BPB 4                       // bands per block (runtime loop)
#define NBLK (NB / BPB)             // 1024 blocks = 4 per CU
#define NT2 256                     // reduce-kernel threads

static constexpr float EPSV = 1e-20f;
static constexpr float LN2  = 0.6931471805599453f;
static constexpr float INV_NBCE = 1.0f / (float)(BATCH * HH * WW);   // bce mean
static constexpr float INV_NM   = 1.0f / (float)(BATCH * PH * PW);   // mse mean

__global__ __launch_bounds__(NT, 4) void srloss_partial(
    const float* __restrict__ output,
    const float* __restrict__ target,
    const float* __restrict__ inp,
    float* __restrict__ partials)
{
    __shared__ float psum[PW];      // pooled column sums for current band
    __shared__ float red[NT / 64];  // cross-wave reduction scratch

    const int t = threadIdx.x;
    const int band0 = blockIdx.x * BPB;

    // c = t + 320k -> row = k, col0 = 4t for all k (band- and k-invariant)
    const int col0 = 4 * t;
    const int p0 = col0 / SC;
    const bool straddle = (col0 % SC) == 8;  // o[2],o[3] belong to p0+1

    float contrib = 0.0f;

    #pragma unroll 1                // runtime loop: keep R4's register budget
    for (int i = 0; i < BPB; ++i) {
        const int band = band0 + i; // BPB | 128 -> same image for all 4 bands
        const int b = band >> 7;    // band / 128
        const int pr = band & 127;  // band % 128

        if (t < PW) psum[t] = 0.0f;
        __syncthreads();

        const size_t base = ((size_t)b * HH + (size_t)pr * SC) * WW;
        const float4* __restrict__ o4p = (const float4*)(output + base) + t;
        const float4* __restrict__ t4p = (const float4*)(target + base) + t;

        // R4's depth-5 rotating pipeline body (compiles to 44 VGPR, no spill)
        float4 ob[PD], tb[PD];
        #pragma unroll
        for (int k = 0; k < PD; ++k) {
            ob[k] = o4p[NT * k];
            tb[k] = t4p[NT * k];
        }

        float acc2 = 0.0f;          // sum log2(oc)
        float accd = 0.0f;          // sum t*(log2(om)-log2(oc))
        float s0 = 0.0f, s1 = 0.0f; // pooled sums: halves of the float4
        #pragma unroll
        for (int k = 0; k < KD; ++k) {
            const float4 o4 = ob[k % PD];
            const float4 t4 = tb[k % PD];
            if (k + PD < KD) {      // compile-time after unroll
                ob[k % PD] = o4p[NT * (k + PD)];
                tb[k % PD] = t4p[NT * (k + PD)];
            }
            const float o[4]  = {o4.x, o4.y, o4.z, o4.w};
            const float tg[4] = {t4.x, t4.y, t4.z, t4.w};
            #pragma unroll
            for (int j = 0; j < 4; ++j) {
                const float om = fmaxf(o[j], EPSV);
                const float oc = fmaxf(1.0f - o[j], EPSV);
                const float l1 = __log2f(om);
                const float l2 = __log2f(oc);
                acc2 += l2;
                accd += tg[j] * (l1 - l2);
            }
            s0 += o[0] + o[1];
            s1 += o[2] + o[3];
        }
        const float bce_acc = LN2 * (acc2 + accd);

        if (straddle) {
            atomicAdd(&psum[p0],     s0);
            atomicAdd(&psum[p0 + 1], s1);
        } else {
            atomicAdd(&psum[p0], s0 + s1);
        }
        __syncthreads();

        // MSE terms: one pooled element per thread for t < 128
        float mse_acc = 0.0f;
        if (t < PW) {
            const float pooled = psum[t] * (1.0f / (float)(SC * SC));
            const float iv = inp[(size_t)band * PW + t];
            const float d = iv - pooled;
            mse_acc = d * d;
        }

        contrib += (-INV_NBCE) * bce_acc + INV_NM * mse_acc;
        __syncthreads();            // psum reuse guard before next band
    }

    // block-level reduction of the 4-band contribution
    #pragma unroll
    for (int off = 32; off > 0; off >>= 1)
        contrib += __shfl_down(contrib, off, 64);
    if ((t & 63) == 0) red[t >> 6] = contrib;
    __syncthreads();

    // plain store to a distinct slot: no RMW chain, no fence
    if (t == 0) {
        float s = 0.0f;
        #pragma unroll
        for (int w = 0; w < NT / 64; ++w) s += red[w];
        partials[blockIdx.x] = s;
    }
}

__global__ __launch_bounds__(NT2) void srloss_reduce(
    const float* __restrict__ partials,
    float* __restrict__ out)
{
    __shared__ float red[NT2 / 64];
    const int t = threadIdx.x;

    // 1024 floats = 256 float4; one per thread
    const float4 v = ((const float4*)partials)[t];
    float s = (v.x + v.y) + (v.z + v.w);

    #pragma unroll
    for (int off = 32; off > 0; off >>= 1)
        s += __shfl_down(s, off, 64);
    if ((t & 63) == 0) red[t >> 6] = s;
    __syncthreads();
    if (t == 0) {
        float tot = 0.0f;
        #pragma unroll
        for (int w = 0; w < NT2 / 64; ++w) tot += red[w];
        out[0] = tot;
    }
}

extern "C" void kernel_launch(void* const* d_in, const int* in_sizes, int n_in,
                              void* d_out, int out_size, void* d_ws, size_t ws_size,
                              hipStream_t stream) {
    const float* output = (const float*)d_in[0];
    const float* target = (const float*)d_in[1];
    const float* inp    = (const float*)d_in[2];
    float* out = (float*)d_out;
    float* partials = (float*)d_ws;              // 1024 floats = 4 KB

    srloss_partial<<<NBLK, NT, 0, stream>>>(output, target, inp, partials);
    srloss_reduce<<<1, NT2, 0, stream>>>(partials, out);
}

// Round 8
// 407.143 us; speedup vs baseline: 1.0222x; 1.0222x over previous
//
#include <hip/hip_runtime.h>

// SRLoss: loss = mean((inp - avgpool10x10(output))^2) + BCE(output, target)
// output/target: [32,1,1280,1280] f32; inp: [32,1,128,128] f32; out: scalar f32.
//
// R11 post-mortem: persistent blocks (1024 = 4/CU) did NOT raise occupancy
// (32-34%, same ~10 waves/CU) and dur was unchanged (144us). Both standard
// levers are immovable: hipcc re-sinks register preloads (VGPR pinned 44-48
// across 3 forcing attempts), and residency won't exceed ~2 blocks/CU.
// R12: change the MLP vehicle — __builtin_amdgcn_global_load_lds. Loads go
// straight to LDS with NO VGPR destinations, so the compiler cannot collapse
// them; each thread issues 10 x 16B stages back-to-back = 10KB in flight per
// wave (vs ~1KB). Per band: 2 chunks x 5 rows x (output+target) = 50KB LDS;
// compute reads its own wave's staged bytes (wave-local, barriers for
// safety). LDS 51.8KB -> 3 blocks/CU. Little's law: need 22KB/CU in flight
// for 24.6 GB/s/CU; staging provides ~10x that.
// Signature: LDS ~53KB, Occ ~40-47%. Theory right -> dur 137 -> 75-95us.
// Unchanged -> hard fabric ceiling, XCD-swizzle-or-stop.

#define BATCH 32
#define HH 1280
#define WW 1280
#define PH 128
#define PW 128
#define SC 10
#define NT 320                      // threads per block (5 waves)
#define RPC 5                       // rows staged per chunk
#define NCH 2                       // chunks per band (RPC*NCH = SC)
#define NB (BATCH * PH)             // 4096 bands = 4096 blocks
#define NT2 512                     // reduce-kernel threads

static constexpr float EPSV = 1e-20f;
static constexpr float LN2  = 0.6931471805599453f;
static constexpr float INV_NBCE = 1.0f / (float)(BATCH * HH * WW);   // bce mean
static constexpr float INV_NM   = 1.0f / (float)(BATCH * PH * PW);   // mse mean

// Async global->LDS, 16B per lane. Size arg must be a literal (guide §5).
#define STAGE16(gp, lp)                                                   \
    __builtin_amdgcn_global_load_lds(                                     \
        (const __attribute__((address_space(1))) void*)(const void*)(gp), \
        (__attribute__((address_space(3))) void*)(void*)(lp), 16, 0, 0)

__global__ __launch_bounds__(NT, 4) void srloss_partial(
    const float* __restrict__ output,
    const float* __restrict__ target,
    const float* __restrict__ inp,
    float* __restrict__ partials)
{
    __shared__ float so[RPC * WW];  // 5 rows of output: 25,600 B
    __shared__ float st[RPC * WW];  // 5 rows of target: 25,600 B
    __shared__ float psum[PW];      // pooled column sums for this band
    __shared__ float red[NT / 64];  // cross-wave reduction scratch

    const int t = threadIdx.x;
    const int band = blockIdx.x;    // 0 .. BATCH*PH-1
    const int b = band >> 7;        // band / 128
    const int pr = band & 127;      // band % 128

    if (t < PW) psum[t] = 0.0f;

    const size_t base = ((size_t)b * HH + (size_t)pr * SC) * WW;
    const float* op = output + base + 4 * t;   // per-lane global src, row 0
    const float* tp = target + base + 4 * t;

    // LDS dest: wave-uniform base; HW adds lane*16. Wave w of row r covers
    // bytes [w*1024,(w+1)*1024) -> lane lands exactly at float 4t of the row.
    const int wbase = (t >> 6) << 8;           // wave_id * 256 floats

    // c = 4t for every row -> pooled-column mapping is row-invariant
    const int col0 = 4 * t;
    const int p0 = col0 / SC;
    const bool straddle = (col0 % SC) == 8;    // o[2],o[3] belong to p0+1

    float acc2 = 0.0f;              // sum log2(oc)
    float accd = 0.0f;              // sum t*(log2(om)-log2(oc))
    float s0 = 0.0f, s1 = 0.0f;     // pooled sums: halves of the float4

    #pragma unroll
    for (int h = 0; h < NCH; ++h) {
        __syncthreads();            // guard LDS buffer reuse (h=0: psum init)

        // issue all 10 stages back-to-back: 10 KB in flight per wave,
        // zero VGPR destinations -> compiler cannot collapse this.
        #pragma unroll
        for (int r = 0; r < RPC; ++r) {
            const int row = h * RPC + r;
            STAGE16(op + (size_t)row * WW, &so[r * WW + wbase]);
            STAGE16(tp + (size_t)row * WW, &st[r * WW + wbase]);
        }
        __syncthreads();            // compiler emits s_waitcnt vmcnt(0)
                                    // before s_barrier -> staged data ready

        #pragma unroll
        for (int r = 0; r < RPC; ++r) {
            const float4 o4 = *(const float4*)&so[r * WW + 4 * t];
            const float4 t4 = *(const float4*)&st[r * WW + 4 * t];
            const float o[4]  = {o4.x, o4.y, o4.z, o4.w};
            const float tg[4] = {t4.x, t4.y, t4.z, t4.w};
            #pragma unroll
            for (int j = 0; j < 4; ++j) {
                const float om = fmaxf(o[j], EPSV);
                const float oc = fmaxf(1.0f - o[j], EPSV);
                const float l1 = __log2f(om);
                const float l2 = __log2f(oc);
                acc2 += l2;
                accd += tg[j] * (l1 - l2);
            }
            s0 += o[0] + o[1];
            s1 += o[2] + o[3];
        }
    }
    const float bce_acc = LN2 * (acc2 + accd);

    if (straddle) {
        atomicAdd(&psum[p0],     s0);
        atomicAdd(&psum[p0 + 1], s1);
    } else {
        atomicAdd(&psum[p0], s0 + s1);
    }
    __syncthreads();

    // MSE terms: one pooled element per thread for t < 128
    float mse_acc = 0.0f;
    if (t < PW) {
        const float pooled = psum[t] * (1.0f / (float)(SC * SC));
        const float iv = inp[(size_t)band * PW + t];
        const float d = iv - pooled;
        mse_acc = d * d;
    }

    // per-block contribution, pre-normalized
    float contrib = (-INV_NBCE) * bce_acc + INV_NM * mse_acc;

    #pragma unroll
    for (int off = 32; off > 0; off >>= 1)
        contrib += __shfl_down(contrib, off, 64);
    if ((t & 63) == 0) red[t >> 6] = contrib;
    __syncthreads();

    // plain store to a distinct slot: no RMW chain, no fence
    if (t == 0) {
        float s = 0.0f;
        #pragma unroll
        for (int w = 0; w < NT / 64; ++w) s += red[w];
        partials[band] = s;
    }
}

__global__ __launch_bounds__(NT2) void srloss_reduce(
    const float* __restrict__ partials,
    float* __restrict__ out)
{
    __shared__ float red[NT2 / 64];
    const int t = threadIdx.x;

    // 4096 floats = 1024 float4; 512 threads x 2 float4 each
    const float4 v0 = ((const float4*)partials)[t];
    const float4 v1 = ((const float4*)partials)[t + NT2];
    float s = (v0.x + v0.y) + (v0.z + v0.w) + (v1.x + v1.y) + (v1.z + v1.w);

    #pragma unroll
    for (int off = 32; off > 0; off >>= 1)
        s += __shfl_down(s, off, 64);
    if ((t & 63) == 0) red[t >> 6] = s;
    __syncthreads();
    if (t == 0) {
        float tot = 0.0f;
        #pragma unroll
        for (int w = 0; w < NT2 / 64; ++w) tot += red[w];
        out[0] = tot;
    }
}

extern "C" void kernel_launch(void* const* d_in, const int* in_sizes, int n_in,
                              void* d_out, int out_size, void* d_ws, size_t ws_size,
                              hipStream_t stream) {
    const float* output = (const float*)d_in[0];
    const float* target = (const float*)d_in[1];
    const float* inp    = (const float*)d_in[2];
    float* out = (float*)d_out;
    float* partials = (float*)d_ws;              // 4096 floats = 16 KB

    srloss_partial<<<NB, NT, 0, stream>>>(output, target, inp, partials);
    srloss_reduce<<<1, NT2, 0, stream>>>(partials, out);
}

// Round 9
// 406.826 us; speedup vs baseline: 1.0230x; 1.0008x over previous
//
#include <hip/hip_runtime.h>

// SRLoss: loss = mean((inp - avgpool10x10(output))^2) + BCE(output, target)
// output/target: [32,1,1280,1280] f32; inp: [32,1,128,128] f32; out: scalar f32.
//
// R12 post-mortem: global_load_lds staging (52KB LDS, 10KB in flight/wave,
// provably different code) changed NOTHING: 136us, 12 GB/s/CU. Per-wave MLP
// is definitively NOT the limiter. The one axis never varied: waves/CU,
// pinned at ~7-10 across all rounds. Little's law now allows only (a) hard
// per-CU outstanding-request cap (~12 GB/s/CU pattern roofline; but m13's
// copy hit 24.6 -> CU can do 2x) or (b) in-flight scales with waves and we
// never had enough.
// R13: 3x the waves. NT 320->640 (10-wave blocks), each thread 5 float4-pairs
// at k-stride 640; col0 = 4*(t%320) stays k-invariant -> psum mapping
// unchanged. One resident block = 10 waves/CU, three = 30. launch_bounds
// (640,8) caps VGPR 64 (body is R4's 44-VGPR form, half the buffers).
// Pre-commit: dur -> 55-80us = wave theory right; unchanged = per-CU cap,
// one nt/stream probe left then roofline. WRITE_SIZE >> 1KB = spill, void.

#define BATCH 32
#define HH 1280
#define WW 1280
#define PH 128
#define PW 128
#define SC 10
#define NT 640                      // threads per block (10 waves)
#define KD 5                        // float4-pair iterations per thread
#define NB (BATCH * PH)             // 4096 bands = 4096 blocks
#define NT2 512                     // reduce-kernel threads

static constexpr float EPSV = 1e-20f;
static constexpr float LN2  = 0.6931471805599453f;
static constexpr float INV_NBCE = 1.0f / (float)(BATCH * HH * WW);   // bce mean
static constexpr float INV_NM   = 1.0f / (float)(BATCH * PH * PW);   // mse mean

__global__ __launch_bounds__(NT, 8) void srloss_partial(
    const float* __restrict__ output,
    const float* __restrict__ target,
    const float* __restrict__ inp,
    float* __restrict__ partials)
{
    __shared__ float psum[PW];      // pooled column sums for this band
    __shared__ float red[NT / 64];  // cross-wave reduction scratch

    const int t = threadIdx.x;
    const int band = blockIdx.x;    // 0 .. BATCH*PH-1
    const int b = band >> 7;        // band / 128
    const int pr = band & 127;      // band % 128

    if (t < PW) psum[t] = 0.0f;
    __syncthreads();                // before any loads issue

    const size_t base = ((size_t)b * HH + (size_t)pr * SC) * WW;
    const float4* __restrict__ o4p = (const float4*)(output + base) + t;
    const float4* __restrict__ t4p = (const float4*)(target + base) + t;

    // preload all 5 pairs (compiler will schedule as it likes — the variable
    // under test this round is WAVES, not per-wave pipelining)
    float4 ob[KD], tb[KD];
    #pragma unroll
    for (int k = 0; k < KD; ++k) {
        ob[k] = o4p[NT * k];
        tb[k] = t4p[NT * k];
    }

    // float4 index t + 640k -> row = (t+640k)/320, col4 = t%320 (k-invariant)
    const int col0 = 4 * (t & 319) + ((t & 319) == t ? 0 : 0); // 4*(t%320)
    const int c320 = (t >= 320) ? (t - 320) : t;               // t % 320
    const int c0 = 4 * c320;
    const int p0 = c0 / SC;
    const bool straddle = (c0 % SC) == 8;   // elems 2,3 belong to p0+1

    float acc2 = 0.0f;              // sum log2(oc)
    float accd = 0.0f;              // sum t*(log2(om)-log2(oc))
    float s0 = 0.0f, s1 = 0.0f;     // pooled sums: halves of the float4
    #pragma unroll
    for (int k = 0; k < KD; ++k) {
        const float o[4]  = {ob[k].x, ob[k].y, ob[k].z, ob[k].w};
        const float tg[4] = {tb[k].x, tb[k].y, tb[k].z, tb[k].w};
        #pragma unroll
        for (int j = 0; j < 4; ++j) {
            const float om = fmaxf(o[j], EPSV);
            const float oc = fmaxf(1.0f - o[j], EPSV);
            const float l1 = __log2f(om);
            const float l2 = __log2f(oc);
            acc2 += l2;
            accd += tg[j] * (l1 - l2);
        }
        s0 += o[0] + o[1];
        s1 += o[2] + o[3];
    }
    const float bce_acc = LN2 * (acc2 + accd);

    if (straddle) {
        atomicAdd(&psum[p0],     s0);
        atomicAdd(&psum[p0 + 1], s1);
    } else {
        atomicAdd(&psum[p0], s0 + s1);
    }
    __syncthreads();

    // MSE terms: one pooled element per thread for t < 128
    float mse_acc = 0.0f;
    if (t < PW) {
        const float pooled = psum[t] * (1.0f / (float)(SC * SC));
        const float iv = inp[(size_t)band * PW + t];
        const float d = iv - pooled;
        mse_acc = d * d;
    }

    // per-block contribution, pre-normalized
    float contrib = (-INV_NBCE) * bce_acc + INV_NM * mse_acc;

    #pragma unroll
    for (int off = 32; off > 0; off >>= 1)
        contrib += __shfl_down(contrib, off, 64);
    if ((t & 63) == 0) red[t >> 6] = contrib;
    __syncthreads();

    // plain store to a distinct slot: no RMW chain, no fence
    if (t == 0) {
        float s = 0.0f;
        #pragma unroll
        for (int w = 0; w < NT / 64; ++w) s += red[w];
        partials[band] = s;
    }
}

__global__ __launch_bounds__(NT2) void srloss_reduce(
    const float* __restrict__ partials,
    float* __restrict__ out)
{
    __shared__ float red[NT2 / 64];
    const int t = threadIdx.x;

    // 4096 floats = 1024 float4; 512 threads x 2 float4 each
    const float4 v0 = ((const float4*)partials)[t];
    const float4 v1 = ((const float4*)partials)[t + NT2];
    float s = (v0.x + v0.y) + (v0.z + v0.w) + (v1.x + v1.y) + (v1.z + v1.w);

    #pragma unroll
    for (int off = 32; off > 0; off >>= 1)
        s += __shfl_down(s, off, 64);
    if ((t & 63) == 0) red[t >> 6] = s;
    __syncthreads();
    if (t == 0) {
        float tot = 0.0f;
        #pragma unroll
        for (int w = 0; w < NT2 / 64; ++w) tot += red[w];
        out[0] = tot;
    }
}

extern "C" void kernel_launch(void* const* d_in, const int* in_sizes, int n_in,
                              void* d_out, int out_size, void* d_ws, size_t ws_size,
                              hipStream_t stream) {
    const float* output = (const float*)d_in[0];
    const float* target = (const float*)d_in[1];
    const float* inp    = (const float*)d_in[2];
    float* out = (float*)d_out;
    float* partials = (float*)d_ws;              // 4096 floats = 16 KB

    srloss_partial<<<NB, NT, 0, stream>>>(output, target, inp, partials);
    srloss_reduce<<<1, NT2, 0, stream>>>(partials, out);
}

// Round 10
// 376.510 us; speedup vs baseline: 1.1054x; 1.0805x over previous
//
#include <hip/hip_runtime.h>

// SRLoss: loss = mean((inp - avgpool10x10(output))^2) + BCE(output, target)
// output/target: [32,1,1280,1280] f32; inp: [32,1,128,128] f32; out: scalar f32.
//
// R13 post-mortem: 640-thread blocks raised occupancy 30->47% (15 waves/CU);
// dur unchanged 137us. With R12 (10x per-wave in-flight, unchanged) this
// closes the arc: delivery is pinned at 3.04 TB/s of load-return regardless
// of waves, MLP, staging vehicle, atomics, or grid shape. m13's copy does
// 3.15 TB/s read + 3.15 write -> we run at 97% of the copy's READ-side rate.
// Theory A (roofline): L2-miss<->memory fabric caps ~3.1 TB/s per direction;
// floor = 419MB/3.15 = 133us, we're at 136. Theory B (fixable): 50% L3 hit
// rate means every request pays Infinity-Cache lookup/fill/evict while
// 421MB thrashes 256MB; streaming loads that bypass the cache relieve it.
// R14 discriminates: R7's exact kernel (137us control), ONLY change =
// __builtin_nontemporal_load on the two streams.
// Signature nt took: FETCH 206 -> ~420MB. B right: dur -> 75-95us.
// A right: dur 133-150us -> declare ROOFLINE next round.

#define BATCH 32
#define HH 1280
#define WW 1280
#define PH 128
#define PW 128
#define SC 10
#define NT 320                      // threads per block (5 waves)
#define KD 10                      // float4-pair iterations per thread
#define PD 5                       // software-pipeline depth
#define NB (BATCH * PH)            // 4096 blocks
#define NT2 512                    // reduce-kernel threads

typedef float f32x4 __attribute__((ext_vector_type(4)));

static constexpr float EPSV = 1e-20f;
static constexpr float LN2  = 0.6931471805599453f;
static constexpr float INV_NBCE = 1.0f / (float)(BATCH * HH * WW);   // bce mean
static constexpr float INV_NM   = 1.0f / (float)(BATCH * PH * PW);   // mse mean

__device__ __forceinline__ f32x4 ntload4(const f32x4* p) {
    return __builtin_nontemporal_load(p);
}

__global__ __launch_bounds__(NT, 4) void srloss_partial(
    const float* __restrict__ output,
    const float* __restrict__ target,
    const float* __restrict__ inp,
    float* __restrict__ partials)
{
    __shared__ float psum[PW];      // pooled column sums for this band
    __shared__ float red[NT / 64];  // cross-wave reduction scratch

    const int t = threadIdx.x;
    const int band = blockIdx.x;    // 0 .. BATCH*PH-1
    const int b = band >> 7;        // band / 128
    const int pr = band & 127;      // band % 128

    if (t < PW) psum[t] = 0.0f;
    __syncthreads();                // before any loads issue

    const size_t base = ((size_t)b * HH + (size_t)pr * SC) * WW;
    const f32x4* __restrict__ o4p = (const f32x4*)(output + base) + t;
    const f32x4* __restrict__ t4p = (const f32x4*)(target + base) + t;

    // depth-5 rotating pipeline, loads marked non-temporal (stream past L3)
    f32x4 ob[PD], tb[PD];
    #pragma unroll
    for (int k = 0; k < PD; ++k) {
        ob[k] = ntload4(o4p + NT * k);
        tb[k] = ntload4(t4p + NT * k);
    }

    float acc2 = 0.0f;              // sum log2(oc)
    float accd = 0.0f;              // sum t*(log2(om)-log2(oc))
    float s0 = 0.0f, s1 = 0.0f;     // pooled sums: halves of the float4
    #pragma unroll
    for (int k = 0; k < KD; ++k) {
        const f32x4 o4 = ob[k % PD];
        const f32x4 t4 = tb[k % PD];
        if (k + PD < KD) {          // compile-time after unroll
            ob[k % PD] = ntload4(o4p + NT * (k + PD));
            tb[k % PD] = ntload4(t4p + NT * (k + PD));
        }
        #pragma unroll
        for (int j = 0; j < 4; ++j) {
            const float oj = o4[j];
            const float om = fmaxf(oj, EPSV);
            const float oc = fmaxf(1.0f - oj, EPSV);
            const float l1 = __log2f(om);
            const float l2 = __log2f(oc);
            acc2 += l2;
            accd += t4[j] * (l1 - l2);
        }
        s0 += o4[0] + o4[1];
        s1 += o4[2] + o4[3];
    }
    const float bce_acc = LN2 * (acc2 + accd);

    // c = t + 320k -> row = k, col0 = 4t for all k (k-invariant mapping)
    const int col0 = 4 * t;
    const int p0 = col0 / SC;
    if ((col0 % SC) == 8) {         // straddle: elems 2,3 belong to p0+1
        atomicAdd(&psum[p0],     s0);
        atomicAdd(&psum[p0 + 1], s1);
    } else {
        atomicAdd(&psum[p0], s0 + s1);
    }
    __syncthreads();

    // MSE terms: one pooled element per thread for t < 128
    float mse_acc = 0.0f;
    if (t < PW) {
        const float pooled = psum[t] * (1.0f / (float)(SC * SC));
        const float iv = inp[(size_t)band * PW + t];
        const float d = iv - pooled;
        mse_acc = d * d;
    }

    // per-block contribution, pre-normalized
    float contrib = (-INV_NBCE) * bce_acc + INV_NM * mse_acc;

    #pragma unroll
    for (int off = 32; off > 0; off >>= 1)
        contrib += __shfl_down(contrib, off, 64);
    if ((t & 63) == 0) red[t >> 6] = contrib;
    __syncthreads();

    // plain store to a distinct slot: no RMW chain, no fence
    if (t == 0) {
        float s = 0.0f;
        #pragma unroll
        for (int w = 0; w < NT / 64; ++w) s += red[w];
        partials[band] = s;
    }
}

__global__ __launch_bounds__(NT2) void srloss_reduce(
    const float* __restrict__ partials,
    float* __restrict__ out)
{
    __shared__ float red[NT2 / 64];
    const int t = threadIdx.x;

    // 4096 floats = 1024 float4; 512 threads x 2 float4 each
    const f32x4 v0 = ((const f32x4*)partials)[t];
    const f32x4 v1 = ((const f32x4*)partials)[t + NT2];
    float s = (v0[0] + v0[1]) + (v0[2] + v0[3]) + (v1[0] + v1[1]) + (v1[2] + v1[3]);

    #pragma unroll
    for (int off = 32; off > 0; off >>= 1)
        s += __shfl_down(s, off, 64);
    if ((t & 63) == 0) red[t >> 6] = s;
    __syncthreads();
    if (t == 0) {
        float tot = 0.0f;
        #pragma unroll
        for (int w = 0; w < NT2 / 64; ++w) tot += red[w];
        out[0] = tot;
    }
}

extern "C" void kernel_launch(void* const* d_in, const int* in_sizes, int n_in,
                              void* d_out, int out_size, void* d_ws, size_t ws_size,
                              hipStream_t stream) {
    const float* output = (const float*)d_in[0];
    const float* target = (const float*)d_in[1];
    const float* inp    = (const float*)d_in[2];
    float* out = (float*)d_out;
    float* partials = (float*)d_ws;              // 4096 floats = 16 KB

    srloss_partial<<<NB, NT, 0, stream>>>(output, target, inp, partials);
    srloss_reduce<<<1, NT2, 0, stream>>>(partials, out);
}

// Round 11
// 374.759 us; speedup vs baseline: 1.1105x; 1.0047x over previous
//
#include <hip/hip_runtime.h>

// SRLoss: loss = mean((inp - avgpool10x10(output))^2) + BCE(output, target)
// output/target: [32,1,1280,1280] f32; inp: [32,1,128,128] f32; out: scalar f32.
//
// R14 post-mortem: NON-TEMPORAL LOADS WORKED — bench 407 -> 376.5us, partial
// kernel ~137 -> ~107us (dropped out of top-5 under the 123us harness fills).
// The 3.05 TB/s plateau was L3 lookup/fill/evict on a thrashing 421MB
// stream, not a fabric wall. Harness fills show 6.8 TB/s write headroom.
// R15: now at ~3.9 TB/s read; with L3 bypassed, loads run at full HBM
// latency (~900ns) -> Little's law needs ~22KB in flight/CU for 24.6
// GB/s/CU; at 10 waves/CU x 2KB we're marginal. The wave-count lever (R13:
// null under the old 3.05 cap) has never been tested under nt — re-apply it:
// NT=640 (10-wave blocks, R13's validated mapping) + nt loads.
// Prediction: latency-bound -> partial ~75-90us, bench ~345-360. Unchanged
// -> 3.9 TB/s is the nt-path ceiling, declare roofline next round.

#define BATCH 32
#define HH 1280
#define WW 1280
#define PH 128
#define PW 128
#define SC 10
#define NT 640                      // threads per block (10 waves)
#define KD 5                        // float4-pair iterations per thread
#define NB (BATCH * PH)             // 4096 bands = 4096 blocks
#define NT2 512                     // reduce-kernel threads

typedef float f32x4 __attribute__((ext_vector_type(4)));

static constexpr float EPSV = 1e-20f;
static constexpr float LN2  = 0.6931471805599453f;
static constexpr float INV_NBCE = 1.0f / (float)(BATCH * HH * WW);   // bce mean
static constexpr float INV_NM   = 1.0f / (float)(BATCH * PH * PW);   // mse mean

__device__ __forceinline__ f32x4 ntload4(const f32x4* p) {
    return __builtin_nontemporal_load(p);
}

__global__ __launch_bounds__(NT, 8) void srloss_partial(
    const float* __restrict__ output,
    const float* __restrict__ target,
    const float* __restrict__ inp,
    float* __restrict__ partials)
{
    __shared__ float psum[PW];      // pooled column sums for this band
    __shared__ float red[NT / 64];  // cross-wave reduction scratch

    const int t = threadIdx.x;
    const int band = blockIdx.x;    // 0 .. BATCH*PH-1
    const int b = band >> 7;        // band / 128
    const int pr = band & 127;      // band % 128

    if (t < PW) psum[t] = 0.0f;
    __syncthreads();                // before any loads issue

    const size_t base = ((size_t)b * HH + (size_t)pr * SC) * WW;
    const f32x4* __restrict__ o4p = (const f32x4*)(output + base) + t;
    const f32x4* __restrict__ t4p = (const f32x4*)(target + base) + t;

    // full preload of all 5 pairs, non-temporal (bypass L3)
    f32x4 ob[KD], tb[KD];
    #pragma unroll
    for (int k = 0; k < KD; ++k) {
        ob[k] = ntload4(o4p + NT * k);
        tb[k] = ntload4(t4p + NT * k);
    }

    // float4 index t + 640k -> row = idx/320, col4 = t%320 (k-invariant)
    const int c320 = (t >= 320) ? (t - 320) : t;   // t % 320
    const int c0 = 4 * c320;
    const int p0 = c0 / SC;
    const bool straddle = (c0 % SC) == 8;          // elems 2,3 belong to p0+1

    float acc2 = 0.0f;              // sum log2(oc)
    float accd = 0.0f;              // sum t*(log2(om)-log2(oc))
    float s0 = 0.0f, s1 = 0.0f;     // pooled sums: halves of the float4
    #pragma unroll
    for (int k = 0; k < KD; ++k) {
        const f32x4 o4 = ob[k];
        const f32x4 t4 = tb[k];
        #pragma unroll
        for (int j = 0; j < 4; ++j) {
            const float oj = o4[j];
            const float om = fmaxf(oj, EPSV);
            const float oc = fmaxf(1.0f - oj, EPSV);
            const float l1 = __log2f(om);
            const float l2 = __log2f(oc);
            acc2 += l2;
            accd += t4[j] * (l1 - l2);
        }
        s0 += o4[0] + o4[1];
        s1 += o4[2] + o4[3];
    }
    const float bce_acc = LN2 * (acc2 + accd);

    if (straddle) {
        atomicAdd(&psum[p0],     s0);
        atomicAdd(&psum[p0 + 1], s1);
    } else {
        atomicAdd(&psum[p0], s0 + s1);
    }
    __syncthreads();

    // MSE terms: one pooled element per thread for t < 128
    float mse_acc = 0.0f;
    if (t < PW) {
        const float pooled = psum[t] * (1.0f / (float)(SC * SC));
        const float iv = inp[(size_t)band * PW + t];
        const float d = iv - pooled;
        mse_acc = d * d;
    }

    // per-block contribution, pre-normalized
    float contrib = (-INV_NBCE) * bce_acc + INV_NM * mse_acc;

    #pragma unroll
    for (int off = 32; off > 0; off >>= 1)
        contrib += __shfl_down(contrib, off, 64);
    if ((t & 63) == 0) red[t >> 6] = contrib;
    __syncthreads();

    // plain store to a distinct slot: no RMW chain, no fence
    if (t == 0) {
        float s = 0.0f;
        #pragma unroll
        for (int w = 0; w < NT / 64; ++w) s += red[w];
        partials[band] = s;
    }
}

__global__ __launch_bounds__(NT2) void srloss_reduce(
    const float* __restrict__ partials,
    float* __restrict__ out)
{
    __shared__ float red[NT2 / 64];
    const int t = threadIdx.x;

    // 4096 floats = 1024 float4; 512 threads x 2 float4 each
    const f32x4 v0 = ((const f32x4*)partials)[t];
    const f32x4 v1 = ((const f32x4*)partials)[t + NT2];
    float s = (v0[0] + v0[1]) + (v0[2] + v0[3]) + (v1[0] + v1[1]) + (v1[2] + v1[3]);

    #pragma unroll
    for (int off = 32; off > 0; off >>= 1)
        s += __shfl_down(s, off, 64);
    if ((t & 63) == 0) red[t >> 6] = s;
    __syncthreads();
    if (t == 0) {
        float tot = 0.0f;
        #pragma unroll
        for (int w = 0; w < NT2 / 64; ++w) tot += red[w];
        out[0] = tot;
    }
}

extern "C" void kernel_launch(void* const* d_in, const int* in_sizes, int n_in,
                              void* d_out, int out_size, void* d_ws, size_t ws_size,
                              hipStream_t stream) {
    const float* output = (const float*)d_in[0];
    const float* target = (const float*)d_in[1];
    const float* inp    = (const float*)d_in[2];
    float* out = (float*)d_out;
    float* partials = (float*)d_ws;              // 4096 floats = 16 KB

    srloss_partial<<<NB, NT, 0, stream>>>(output, target, inp, partials);
    srloss_reduce<<<1, NT2, 0, stream>>>(partials, out);
}